// Round 1
// baseline (108.071 us; speedup 1.0000x reference)
//
#include <hip/hip_runtime.h>
#include <hip/hip_bf16.h>
#include <math.h>

// B=2, S=1024, D=512, H=8, hd=64.  M = B*S = 2048.
// Chunked causal linear attention, chunk C=128, NC=8 chunks, BH = B*H = 16.

typedef __bf16 bf16x8 __attribute__((ext_vector_type(8)));
typedef float f32x4 __attribute__((ext_vector_type(4)));

#define MFMA16(a, b, c) __builtin_amdgcn_mfma_f32_16x16x32_bf16(a, b, c, 0, 0, 0)

__device__ __forceinline__ float elu1(float v) { return v > 0.f ? v + 1.f : __expf(v); }

// ---------------------------------------------------------------- convert x -> bf16
__global__ __launch_bounds__(256) void conv_x_kernel(const float* __restrict__ x,
                                                     __bf16* __restrict__ xb) {
    int idx = blockIdx.x * 256 + threadIdx.x;
    int base = idx * 8;
    bf16x8 o;
#pragma unroll
    for (int j = 0; j < 8; j++) o[j] = (__bf16)x[base + j];
    *(bf16x8*)&xb[base] = o;
}

// ---------------------------------------------------------------- transpose fp32 [R][C] -> bf16 [C][R]
__global__ __launch_bounds__(256) void transpose_conv_kernel(const float* __restrict__ in,
                                                             __bf16* __restrict__ out,
                                                             int R, int C) {
    __shared__ float t[32][33];
    int bx = blockIdx.x;  // over C/32
    int by = blockIdx.y;  // over R/32
    int tx = threadIdx.x & 31, ty = threadIdx.x >> 5;
#pragma unroll
    for (int i = 0; i < 32; i += 8)
        t[ty + i][tx] = in[(size_t)(by * 32 + ty + i) * C + bx * 32 + tx];
    __syncthreads();
#pragma unroll
    for (int i = 0; i < 32; i += 8)
        out[(size_t)(bx * 32 + ty + i) * R + by * 32 + tx] = (__bf16)t[tx][ty + i];
}

// ---------------------------------------------------------------- main GEMM (128x128 tile, BK=32)
// A row-major [M][K] bf16 ; Bw row-major [N][K] bf16 (i.e. B^T) ; fp32 accum.
// MODE 0: qkv epilogue (elu+1 on q,k; scatter to per-head layouts)
// MODE 1: proj epilogue (+bo, store fp32 + bf16)
// MODE 2: gate epilogue (A split xb|projb, +bg, sigmoid, final residual mix)
template <int MODE>
__global__ __launch_bounds__(256) void gemm_kernel(
    const __bf16* __restrict__ A, const __bf16* __restrict__ A2,
    const __bf16* __restrict__ Bw, const float* __restrict__ bias,
    const float* __restrict__ xf, const float* __restrict__ proj,
    float* __restrict__ outf, __bf16* __restrict__ outb,
    __bf16* __restrict__ q_out, __bf16* __restrict__ k_out,
    __bf16* __restrict__ kt_out, __bf16* __restrict__ vt_out, int K) {
    __shared__ __bf16 sA[128 * 32];
    __shared__ __bf16 sB[128 * 32];
    int bm = blockIdx.x, bn = blockIdx.y;
    int tid = threadIdx.x, w = tid >> 6, l = tid & 63;
    int wr = (w >> 1) * 64, wc = (w & 1) * 64;
    f32x4 acc[4][4] = {};

    for (int k0 = 0; k0 < K; k0 += 32) {
        __syncthreads();
#pragma unroll
        for (int i = 0; i < 2; i++) {
            int r = i * 64 + (tid >> 2);
            int c = (tid & 3) * 8;
            int gk = k0 + c;
            const __bf16* a0;
            int lda, gka = gk;
            if (MODE == 2) {
                lda = 512;
                if (gk < 512) { a0 = A; } else { a0 = A2; gka = gk - 512; }
            } else { a0 = A; lda = K; }
            *(bf16x8*)&sA[r * 32 + c] = *(const bf16x8*)&a0[(size_t)(bm * 128 + r) * lda + gka];
            *(bf16x8*)&sB[r * 32 + c] = *(const bf16x8*)&Bw[(size_t)(bn * 128 + r) * K + gk];
        }
        __syncthreads();
        frag_compute: ;
        bf16x8 af[4], bfr[4];
#pragma unroll
        for (int mi = 0; mi < 4; mi++)
            af[mi] = *(const bf16x8*)&sA[(wr + mi * 16 + (l & 15)) * 32 + ((l >> 4) << 3)];
#pragma unroll
        for (int ni = 0; ni < 4; ni++)
            bfr[ni] = *(const bf16x8*)&sB[(wc + ni * 16 + (l & 15)) * 32 + ((l >> 4) << 3)];
#pragma unroll
        for (int mi = 0; mi < 4; mi++)
#pragma unroll
            for (int ni = 0; ni < 4; ni++)
                acc[mi][ni] = MFMA16(af[mi], bfr[ni], acc[mi][ni]);
    }

#pragma unroll
    for (int mi = 0; mi < 4; mi++)
#pragma unroll
        for (int ni = 0; ni < 4; ni++)
#pragma unroll
            for (int j = 0; j < 4; j++) {
                int gm = bm * 128 + wr + mi * 16 + ((l >> 4) << 2) + j;
                int gn = bn * 128 + wc + ni * 16 + (l & 15);
                float v = acc[mi][ni][j];
                if (MODE == 0) {
                    int which = gn >> 9;
                    int h = (gn >> 6) & 7;
                    int d = gn & 63;
                    int b = gm >> 10;
                    int s = gm & 1023;
                    int bh = b * 8 + h;
                    if (which == 0) {
                        q_out[((size_t)(bh * 1024 + s)) * 64 + d] = (__bf16)elu1(v);
                    } else if (which == 1) {
                        __bf16 tb = (__bf16)elu1(v);
                        k_out[((size_t)(bh * 1024 + s)) * 64 + d] = tb;
                        kt_out[((size_t)(bh * 64 + d)) * 1024 + s] = tb;
                    } else {
                        vt_out[((size_t)(bh * 64 + d)) * 1024 + s] = (__bf16)v;
                    }
                } else if (MODE == 1) {
                    v += bias[gn];
                    outf[(size_t)gm * 512 + gn] = v;
                    outb[(size_t)gm * 512 + gn] = (__bf16)v;
                } else {
                    v += bias[gn];
                    float g = 1.f / (1.f + __expf(-v));
                    float xv = xf[(size_t)gm * 512 + gn];
                    float pv = proj[(size_t)gm * 512 + gn];
                    outf[(size_t)gm * 512 + gn] = xv + g * (pv - xv);
                }
            }
}

// ---------------------------------------------------------------- pass A: per-chunk M = V^T K (64x64x128) + ksum
__global__ __launch_bounds__(64) void chunk_sum_kernel(const __bf16* __restrict__ ktb,
                                                       const __bf16* __restrict__ vtb,
                                                       float* __restrict__ Mc,
                                                       float* __restrict__ ksum_c) {
    int blk = blockIdx.x;          // bh*8 + ch
    int bh = blk >> 3, ch = blk & 7;
    int l = threadIdx.x;
    f32x4 acc[4][4] = {};
    const __bf16* abase = vtb + (size_t)bh * 64 * 1024 + ch * 128;
    const __bf16* bbase = ktb + (size_t)bh * 64 * 1024 + ch * 128;
#pragma unroll
    for (int ks = 0; ks < 4; ks++) {
        bf16x8 a[4], bfr[4];
#pragma unroll
        for (int mi = 0; mi < 4; mi++)
            a[mi] = *(const bf16x8*)&abase[(size_t)(mi * 16 + (l & 15)) * 1024 + ks * 32 + ((l >> 4) << 3)];
#pragma unroll
        for (int ni = 0; ni < 4; ni++)
            bfr[ni] = *(const bf16x8*)&bbase[(size_t)(ni * 16 + (l & 15)) * 1024 + ks * 32 + ((l >> 4) << 3)];
#pragma unroll
        for (int mi = 0; mi < 4; mi++)
#pragma unroll
            for (int ni = 0; ni < 4; ni++)
                acc[mi][ni] = MFMA16(a[mi], bfr[ni], acc[mi][ni]);
    }
#pragma unroll
    for (int mi = 0; mi < 4; mi++)
#pragma unroll
        for (int ni = 0; ni < 4; ni++)
#pragma unroll
            for (int j = 0; j < 4; j++)
                Mc[(size_t)blk * 4096 + (size_t)(mi * 16 + ((l >> 4) << 2) + j) * 64 + ni * 16 + (l & 15)] =
                    acc[mi][ni][j];
    // ksum over the chunk for this lane's k-feature row
    float s = 0.f;
    const __bf16* kr = ktb + (size_t)(bh * 64 + l) * 1024 + ch * 128;
#pragma unroll 16
    for (int t = 0; t < 128; t++) s += (float)kr[t];
    ksum_c[blk * 64 + l] = s;
}

// ---------------------------------------------------------------- pass B: exclusive prefix over chunks
__global__ __launch_bounds__(256) void prefix_kernel(const float* __restrict__ Mc,
                                                     const float* __restrict__ ksum_c,
                                                     __bf16* __restrict__ Mstate,
                                                     float* __restrict__ ksum_state) {
    int bh = blockIdx.x, tid = threadIdx.x;
    for (int i = 0; i < 16; i++) {
        int idx = i * 256 + tid;
        float run = 0.f;
#pragma unroll
        for (int c = 0; c < 8; c++) {
            Mstate[(size_t)(bh * 8 + c) * 4096 + idx] = (__bf16)run;
            run += Mc[(size_t)(bh * 8 + c) * 4096 + idx];
        }
    }
    if (tid < 64) {
        float run = 0.f;
#pragma unroll
        for (int c = 0; c < 8; c++) {
            ksum_state[(bh * 8 + c) * 64 + tid] = run;
            run += ksum_c[(bh * 8 + c) * 64 + tid];
        }
    }
}

// ---------------------------------------------------------------- pass C: per-chunk causal attention
__global__ __launch_bounds__(256) void attn_chunk_kernel(
    const __bf16* __restrict__ qb, const __bf16* __restrict__ kb,
    const __bf16* __restrict__ vtb, const __bf16* __restrict__ Mstate,
    const float* __restrict__ ksum_state, __bf16* __restrict__ attn_out) {
    int blk = blockIdx.x;
    int bh = blk >> 3, ch = blk & 7;
    int b = bh >> 3, h = bh & 7;
    int tid = threadIdx.x, w = tid >> 6, l = tid & 63;

    __shared__ __bf16 sQ[128 * 72];
    __shared__ __bf16 sP[128 * 132];
    __shared__ float den2[128];
    __shared__ float dpart[2][128];
    __shared__ float ksst[64];

    // stage Q chunk [128][64] -> padded LDS
    const __bf16* qsrc = qb + (size_t)(bh * 1024 + ch * 128) * 64;
#pragma unroll
    for (int i = 0; i < 4; i++) {
        int e = i * 2048 + tid * 8;
        int r = e >> 6, c0 = e & 63;
        *(bf16x8*)&sQ[r * 72 + c0] = *(const bf16x8*)&qsrc[e];
    }
    if (tid < 64) ksst[tid] = ksum_state[blk * 64 + tid];
    __syncthreads();

    // den2[i] = q_i . ksum_state
    if (tid < 128) {
        float s = 0.f;
#pragma unroll 8
        for (int d = 0; d < 64; d++) s += (float)sQ[tid * 72 + d] * ksst[d];
        den2[tid] = s;
    }

    // S = Q K^T  (each wave owns 64x64 quadrant: rows wr.., cols wc..)
    int wr = (w >> 1) * 64, wc = (w & 1) * 64;
    f32x4 acc[4][4] = {};
    const __bf16* kbase = kb + (size_t)(bh * 1024 + ch * 128) * 64;
#pragma unroll
    for (int ks = 0; ks < 2; ks++) {
        bf16x8 a[4], bfr[4];
#pragma unroll
        for (int mi = 0; mi < 4; mi++)
            a[mi] = *(const bf16x8*)&sQ[(wr + mi * 16 + (l & 15)) * 72 + ks * 32 + ((l >> 4) << 3)];
#pragma unroll
        for (int ni = 0; ni < 4; ni++)
            bfr[ni] = *(const bf16x8*)&kbase[(size_t)(wc + ni * 16 + (l & 15)) * 64 + ks * 32 + ((l >> 4) << 3)];
#pragma unroll
        for (int mi = 0; mi < 4; mi++)
#pragma unroll
            for (int ni = 0; ni < 4; ni++)
                acc[mi][ni] = MFMA16(a[mi], bfr[ni], acc[mi][ni]);
    }

    // mask (j<=i), row-sums, write P (bf16) to LDS
#pragma unroll
    for (int mi = 0; mi < 4; mi++) {
#pragma unroll
        for (int j = 0; j < 4; j++) {
            int row = wr + mi * 16 + ((l >> 4) << 2) + j;
            float rs = 0.f;
#pragma unroll
            for (int ni = 0; ni < 4; ni++) {
                int col = wc + ni * 16 + (l & 15);
                float v = acc[mi][ni][j];
                v = (col <= row) ? v : 0.f;
                rs += v;
                sP[row * 132 + col] = (__bf16)v;
            }
#pragma unroll
            for (int off = 1; off < 16; off <<= 1) rs += __shfl_xor(rs, off);
            if ((l & 15) == 0) dpart[w & 1][row] = rs;
        }
    }
    __syncthreads();

    // O = P @ V  +  Q @ KV_state   (each wave owns 32 rows x 64 cols)
    f32x4 o[2][4] = {};
    const __bf16* vbase = vtb + (size_t)bh * 64 * 1024 + ch * 128;
    const __bf16* mbase = Mstate + (size_t)blk * 4096;
#pragma unroll
    for (int ks = 0; ks < 4; ks++) {
        bf16x8 a[2], bfr[4];
#pragma unroll
        for (int mi = 0; mi < 2; mi++)
            a[mi] = *(const bf16x8*)&sP[(w * 32 + mi * 16 + (l & 15)) * 132 + ks * 32 + ((l >> 4) << 3)];
#pragma unroll
        for (int ni = 0; ni < 4; ni++)
            bfr[ni] = *(const bf16x8*)&vbase[(size_t)(ni * 16 + (l & 15)) * 1024 + ks * 32 + ((l >> 4) << 3)];
#pragma unroll
        for (int mi = 0; mi < 2; mi++)
#pragma unroll
            for (int ni = 0; ni < 4; ni++)
                o[mi][ni] = MFMA16(a[mi], bfr[ni], o[mi][ni]);
    }
#pragma unroll
    for (int ks = 0; ks < 2; ks++) {
        bf16x8 a[2], bfr[4];
#pragma unroll
        for (int mi = 0; mi < 2; mi++)
            a[mi] = *(const bf16x8*)&sQ[(w * 32 + mi * 16 + (l & 15)) * 72 + ks * 32 + ((l >> 4) << 3)];
#pragma unroll
        for (int ni = 0; ni < 4; ni++)
            bfr[ni] = *(const bf16x8*)&mbase[(size_t)(ni * 16 + (l & 15)) * 64 + ks * 32 + ((l >> 4) << 3)];
#pragma unroll
        for (int mi = 0; mi < 2; mi++)
#pragma unroll
            for (int ni = 0; ni < 4; ni++)
                o[mi][ni] = MFMA16(a[mi], bfr[ni], o[mi][ni]);
    }

    // normalize and write out [B*S][512] at head offset
    __bf16* obase = attn_out + ((size_t)(b * 1024 + ch * 128)) * 512 + h * 64;
#pragma unroll
    for (int mi = 0; mi < 2; mi++)
#pragma unroll
        for (int j = 0; j < 4; j++) {
            int row = w * 32 + mi * 16 + ((l >> 4) << 2) + j;
            float dn = den2[row] + dpart[0][row] + dpart[1][row] + 1e-6f;
#pragma unroll
            for (int ni = 0; ni < 4; ni++) {
                int col = ni * 16 + (l & 15);
                obase[(size_t)row * 512 + col] = (__bf16)(o[mi][ni][j] / dn);
            }
        }
}

// ----------------------------------------------------------------
extern "C" void kernel_launch(void* const* d_in, const int* in_sizes, int n_in,
                              void* d_out, int out_size, void* d_ws, size_t ws_size,
                              hipStream_t stream) {
    const float* x = (const float*)d_in[0];
    const float* Wq = (const float*)d_in[1];
    const float* Wk = (const float*)d_in[2];
    const float* Wv = (const float*)d_in[3];
    const float* Wo = (const float*)d_in[4];
    const float* bo = (const float*)d_in[5];
    const float* Wg = (const float*)d_in[6];
    const float* bg = (const float*)d_in[7];
    float* out = (float*)d_out;

    char* ws = (char*)d_ws;
    size_t off = 0;
    auto alloc = [&](size_t bytes) -> void* {
        void* p = ws + off;
        off += (bytes + 255) & ~(size_t)255;
        return p;
    };
    __bf16* xb    = (__bf16*)alloc((size_t)2048 * 512 * 2);
    __bf16* wqkvT = (__bf16*)alloc((size_t)1536 * 512 * 2);
    __bf16* woT   = (__bf16*)alloc((size_t)512 * 512 * 2);
    __bf16* wgT   = (__bf16*)alloc((size_t)512 * 1024 * 2);
    __bf16* qb    = (__bf16*)alloc((size_t)16 * 1024 * 64 * 2);
    __bf16* kb    = (__bf16*)alloc((size_t)16 * 1024 * 64 * 2);
    __bf16* ktb   = (__bf16*)alloc((size_t)16 * 64 * 1024 * 2);
    __bf16* vtb   = (__bf16*)alloc((size_t)16 * 64 * 1024 * 2);
    float*  Mc    = (float*)alloc((size_t)16 * 8 * 4096 * 4);
    __bf16* Mst   = (__bf16*)alloc((size_t)16 * 8 * 4096 * 2);
    float*  ksc   = (float*)alloc((size_t)16 * 8 * 64 * 4);
    float*  kss   = (float*)alloc((size_t)16 * 8 * 64 * 4);
    __bf16* attn  = (__bf16*)alloc((size_t)2048 * 512 * 2);
    float*  proj  = (float*)alloc((size_t)2048 * 512 * 4);
    __bf16* projb = (__bf16*)alloc((size_t)2048 * 512 * 2);

    conv_x_kernel<<<512, 256, 0, stream>>>(x, xb);
    transpose_conv_kernel<<<dim3(16, 16), 256, 0, stream>>>(Wq, wqkvT, 512, 512);
    transpose_conv_kernel<<<dim3(16, 16), 256, 0, stream>>>(Wk, wqkvT + (size_t)512 * 512, 512, 512);
    transpose_conv_kernel<<<dim3(16, 16), 256, 0, stream>>>(Wv, wqkvT + (size_t)1024 * 512, 512, 512);
    transpose_conv_kernel<<<dim3(16, 16), 256, 0, stream>>>(Wo, woT, 512, 512);
    transpose_conv_kernel<<<dim3(16, 32), 256, 0, stream>>>(Wg, wgT, 1024, 512);

    gemm_kernel<0><<<dim3(16, 12), 256, 0, stream>>>(xb, nullptr, wqkvT, nullptr, nullptr, nullptr,
                                                     nullptr, nullptr, qb, kb, ktb, vtb, 512);
    chunk_sum_kernel<<<128, 64, 0, stream>>>(ktb, vtb, Mc, ksc);
    prefix_kernel<<<16, 256, 0, stream>>>(Mc, ksc, Mst, kss);
    attn_chunk_kernel<<<128, 256, 0, stream>>>(qb, kb, vtb, Mst, kss, attn);
    gemm_kernel<1><<<dim3(16, 4), 256, 0, stream>>>(attn, nullptr, woT, bo, nullptr, nullptr, proj,
                                                    projb, nullptr, nullptr, nullptr, nullptr, 512);
    gemm_kernel<2><<<dim3(16, 4), 256, 0, stream>>>(xb, projb, wgT, bg, x, proj, out, nullptr,
                                                    nullptr, nullptr, nullptr, nullptr, 1024);
}

// Round 2
// 87.854 us; speedup vs baseline: 1.2301x; 1.2301x over previous
//
#include <hip/hip_runtime.h>
#include <hip/hip_bf16.h>
#include <math.h>

// B=2, S=1024, D=512, H=8, hd=64.  M = B*S = 2048.
// Chunked causal linear attention, chunk C=128, NC=8 chunks, BH = B*H = 16.

typedef __bf16 bf16x8 __attribute__((ext_vector_type(8)));
typedef __bf16 bf16x4 __attribute__((ext_vector_type(4)));
typedef float f32x4 __attribute__((ext_vector_type(4)));

#define MFMA16(a, b, c) __builtin_amdgcn_mfma_f32_16x16x32_bf16(a, b, c, 0, 0, 0)

__device__ __forceinline__ float elu1(float v) { return v > 0.f ? v + 1.f : __expf(v); }

// async global->LDS, 16B per lane; lds base must be wave-uniform (HW adds lane*16)
__device__ __forceinline__ void gload16(const void* g, void* l) {
    __builtin_amdgcn_global_load_lds((const __attribute__((address_space(1))) void*)g,
                                     (__attribute__((address_space(3))) void*)l, 16, 0, 0);
}

// ---------------------------------------------------------------- prep: x->bf16 + 5 weight transposes
// z=0..3: 512x512 transpose {Wq,Wk,Wv,Wo}; z=4: Wg 1024x512; z=5: conv x
__global__ __launch_bounds__(256) void prep_kernel(
    const float* __restrict__ x, const float* __restrict__ Wq, const float* __restrict__ Wk,
    const float* __restrict__ Wv, const float* __restrict__ Wo, const float* __restrict__ Wg,
    __bf16* __restrict__ xb, __bf16* __restrict__ wqkvT, __bf16* __restrict__ woT,
    __bf16* __restrict__ wgT) {
    int z = blockIdx.z;
    if (z == 5) {
        int bid = blockIdx.y * 16 + blockIdx.x;
        int base = (bid * 256 + threadIdx.x) * 8;
        bf16x8 o;
#pragma unroll
        for (int j = 0; j < 8; j++) o[j] = (__bf16)x[base + j];
        *(bf16x8*)&xb[base] = o;
        return;
    }
    const float* in;
    __bf16* out;
    int R = 512, C = 512;
    if (z == 0) { in = Wq; out = wqkvT; }
    else if (z == 1) { in = Wk; out = wqkvT + (size_t)512 * 512; }
    else if (z == 2) { in = Wv; out = wqkvT + (size_t)1024 * 512; }
    else if (z == 3) { in = Wo; out = woT; }
    else { in = Wg; out = wgT; R = 1024; }
    if ((int)blockIdx.y * 32 >= R) return;
    __shared__ float t[32][33];
    int bx = blockIdx.x, by = blockIdx.y;
    int tx = threadIdx.x & 31, ty = threadIdx.x >> 5;
#pragma unroll
    for (int i = 0; i < 32; i += 8)
        t[ty + i][tx] = in[(size_t)(by * 32 + ty + i) * C + bx * 32 + tx];
    __syncthreads();
#pragma unroll
    for (int i = 0; i < 32; i += 8)
        out[(size_t)(bx * 32 + ty + i) * R + by * 32 + tx] = (__bf16)t[tx][ty + i];
}

// ---------------------------------------------------------------- main GEMM (128xBN tile, BK=32)
// A row-major [M][K] bf16 ; Bw row-major [N][K] bf16 (B^T) ; fp32 accum; global_load_lds staging.
// MODE 0: qkv epilogue (elu+1 on q,k; scatter to per-head layouts), BN=128
// MODE 1: proj epilogue (+bo, store fp32 + bf16), BN=64
// MODE 2: gate epilogue (A split xb|projb, +bg, sigmoid, final residual mix), BN=64
template <int MODE, int BN>
__global__ __launch_bounds__(256) void gemm_kernel(
    const __bf16* __restrict__ A, const __bf16* __restrict__ A2,
    const __bf16* __restrict__ Bw, const float* __restrict__ bias,
    const float* __restrict__ xf, const float* __restrict__ proj,
    float* __restrict__ outf, __bf16* __restrict__ outb,
    __bf16* __restrict__ q_out, __bf16* __restrict__ k_out,
    __bf16* __restrict__ kt_out, __bf16* __restrict__ vt_out, int K) {
    constexpr int NI = BN / 32;
    __shared__ __bf16 sA[128 * 32];
    __shared__ __bf16 sB[BN * 32];
    int bm = blockIdx.x, bn = blockIdx.y;
    int tid = threadIdx.x, w = tid >> 6, l = tid & 63;
    int wr = (w >> 1) * 64, wc = (w & 1) * (BN / 2);
    int r = tid >> 2, c = (tid & 3) * 8;
    f32x4 acc[4][NI] = {};

    for (int k0 = 0; k0 < K; k0 += 32) {
        __syncthreads();
        const __bf16* a0 = A;
        int gka = k0, lda = K;
        if (MODE == 2) {
            lda = 512;
            if (k0 >= 512) { a0 = A2; gka = k0 - 512; }
        }
#pragma unroll
        for (int i = 0; i < 2; i++)
            gload16(&a0[(size_t)(bm * 128 + i * 64 + r) * lda + gka + c],
                    &sA[i * 2048 + w * 512]);
#pragma unroll
        for (int i = 0; i < BN / 64; i++)
            gload16(&Bw[(size_t)(bn * BN + i * 64 + r) * K + k0 + c],
                    &sB[i * 2048 + w * 512]);
        __syncthreads();
        bf16x8 af[4], bfr[NI];
#pragma unroll
        for (int mi = 0; mi < 4; mi++)
            af[mi] = *(const bf16x8*)&sA[(wr + mi * 16 + (l & 15)) * 32 + ((l >> 4) << 3)];
#pragma unroll
        for (int ni = 0; ni < NI; ni++)
            bfr[ni] = *(const bf16x8*)&sB[(wc + ni * 16 + (l & 15)) * 32 + ((l >> 4) << 3)];
#pragma unroll
        for (int mi = 0; mi < 4; mi++)
#pragma unroll
            for (int ni = 0; ni < NI; ni++)
                acc[mi][ni] = MFMA16(af[mi], bfr[ni], acc[mi][ni]);
    }

    if (MODE == 0) {
#pragma unroll
        for (int mi = 0; mi < 4; mi++) {
            int gm0 = bm * 128 + wr + mi * 16 + ((l >> 4) << 2);
            int b = gm0 >> 10, s0 = gm0 & 1023;
#pragma unroll
            for (int ni = 0; ni < NI; ni++) {
                int gn = bn * BN + wc + ni * 16 + (l & 15);
                int which = gn >> 9, h = (gn >> 6) & 7, d = gn & 63;
                int bh = b * 8 + h;
                if (which == 0) {
#pragma unroll
                    for (int j = 0; j < 4; j++)
                        q_out[((size_t)(bh * 1024 + s0 + j)) * 64 + d] = (__bf16)elu1(acc[mi][ni][j]);
                } else if (which == 1) {
                    bf16x4 pk;
#pragma unroll
                    for (int j = 0; j < 4; j++) {
                        __bf16 tb = (__bf16)elu1(acc[mi][ni][j]);
                        pk[j] = tb;
                        k_out[((size_t)(bh * 1024 + s0 + j)) * 64 + d] = tb;
                    }
                    *(bf16x4*)&kt_out[((size_t)(bh * 64 + d)) * 1024 + s0] = pk;
                } else {
                    bf16x4 pv;
#pragma unroll
                    for (int j = 0; j < 4; j++) pv[j] = (__bf16)acc[mi][ni][j];
                    *(bf16x4*)&vt_out[((size_t)(bh * 64 + d)) * 1024 + s0] = pv;
                }
            }
        }
    } else {
#pragma unroll
        for (int mi = 0; mi < 4; mi++)
#pragma unroll
            for (int ni = 0; ni < NI; ni++)
#pragma unroll
                for (int j = 0; j < 4; j++) {
                    int gm = bm * 128 + wr + mi * 16 + ((l >> 4) << 2) + j;
                    int gn = bn * BN + wc + ni * 16 + (l & 15);
                    float v = acc[mi][ni][j] + bias[gn];
                    if (MODE == 1) {
                        outf[(size_t)gm * 512 + gn] = v;
                        outb[(size_t)gm * 512 + gn] = (__bf16)v;
                    } else {
                        float g = 1.f / (1.f + __expf(-v));
                        float xv = xf[(size_t)gm * 512 + gn];
                        float pv = proj[(size_t)gm * 512 + gn];
                        outf[(size_t)gm * 512 + gn] = xv + g * (pv - xv);
                    }
                }
    }
}

// ---------------------------------------------------------------- chunk states: M_c = V^T K per chunk,
// ksum per chunk, then in-block exclusive prefix over the 8 chunks. One block per bh.
__global__ __launch_bounds__(256) void chunkstate_kernel(
    const __bf16* __restrict__ ktb, const __bf16* __restrict__ vtb,
    float* __restrict__ Mc, __bf16* __restrict__ Mst, float* __restrict__ kss) {
    int bh = blockIdx.x;
    int tid = threadIdx.x, w = tid >> 6, l = tid & 63;
    __shared__ float ksl[8][64];

#pragma unroll
    for (int cc = 0; cc < 2; cc++) {
        int ch = w * 2 + cc;
        const __bf16* abase = vtb + (size_t)bh * 65536 + ch * 128;
        const __bf16* bbase = ktb + (size_t)bh * 65536 + ch * 128;
        f32x4 acc[4][4] = {};
#pragma unroll
        for (int ks = 0; ks < 4; ks++) {
            bf16x8 a[4], bfr[4];
#pragma unroll
            for (int mi = 0; mi < 4; mi++)
                a[mi] = *(const bf16x8*)&abase[(size_t)(mi * 16 + (l & 15)) * 1024 + ks * 32 + ((l >> 4) << 3)];
#pragma unroll
            for (int ni = 0; ni < 4; ni++)
                bfr[ni] = *(const bf16x8*)&bbase[(size_t)(ni * 16 + (l & 15)) * 1024 + ks * 32 + ((l >> 4) << 3)];
#pragma unroll
            for (int mi = 0; mi < 4; mi++)
#pragma unroll
                for (int ni = 0; ni < 4; ni++)
                    acc[mi][ni] = MFMA16(a[mi], bfr[ni], acc[mi][ni]);
        }
        float* mout = Mc + ((size_t)(bh * 8 + ch)) * 4096;
#pragma unroll
        for (int mi = 0; mi < 4; mi++)
#pragma unroll
            for (int ni = 0; ni < 4; ni++)
#pragma unroll
                for (int j = 0; j < 4; j++)
                    mout[(size_t)(mi * 16 + ((l >> 4) << 2) + j) * 64 + ni * 16 + (l & 15)] = acc[mi][ni][j];
    }

    // ksum per chunk, vectorized
#pragma unroll
    for (int cc = 0; cc < 2; cc++) {
        int ch = w * 2 + cc, d = l;
        const __bf16* kr = ktb + (size_t)(bh * 64 + d) * 1024 + ch * 128;
        float s = 0.f;
#pragma unroll
        for (int t = 0; t < 16; t++) {
            bf16x8 v = *(const bf16x8*)&kr[t * 8];
#pragma unroll
            for (int j = 0; j < 8; j++) s += (float)v[j];
        }
        ksl[ch][d] = s;
    }
    __syncthreads();

    // exclusive prefix over chunks (Mc in global just written by this block; barrier made it visible)
    const float* mcb = Mc + (size_t)bh * 32768;
    __bf16* msb = Mst + (size_t)bh * 32768;
#pragma unroll
    for (int i = 0; i < 16; i++) {
        int idx = i * 256 + tid;
        float run = 0.f;
#pragma unroll
        for (int c2 = 0; c2 < 8; c2++) {
            msb[(size_t)c2 * 4096 + idx] = (__bf16)run;
            run += mcb[(size_t)c2 * 4096 + idx];
        }
    }
    if (tid < 64) {
        float run = 0.f;
#pragma unroll
        for (int c2 = 0; c2 < 8; c2++) {
            kss[(bh * 8 + c2) * 64 + tid] = run;
            run += ksl[c2][tid];
        }
    }
}

// ---------------------------------------------------------------- per-chunk causal attention
__global__ __launch_bounds__(256) void attn_chunk_kernel(
    const __bf16* __restrict__ qb, const __bf16* __restrict__ kb,
    const __bf16* __restrict__ vtb, const __bf16* __restrict__ Mstate,
    const float* __restrict__ ksum_state, __bf16* __restrict__ attn_out) {
    int blk = blockIdx.x;
    int bh = blk >> 3, ch = blk & 7;
    int b = bh >> 3, h = bh & 7;
    int tid = threadIdx.x, w = tid >> 6, l = tid & 63;

    __shared__ __bf16 sQ[128 * 72];
    __shared__ __bf16 sP[128 * 132];
    __shared__ float den2[128];
    __shared__ float dpart[2][128];
    __shared__ float ksst[64];

    // stage Q chunk [128][64] -> padded LDS
    const __bf16* qsrc = qb + (size_t)(bh * 1024 + ch * 128) * 64;
#pragma unroll
    for (int i = 0; i < 4; i++) {
        int e = i * 2048 + tid * 8;
        int rr = e >> 6, c0 = e & 63;
        *(bf16x8*)&sQ[rr * 72 + c0] = *(const bf16x8*)&qsrc[e];
    }
    if (tid < 64) ksst[tid] = ksum_state[blk * 64 + tid];
    __syncthreads();

    // den2[i] = q_i . ksum_state  (2 threads per row)
    {
        int row = tid >> 1, hf = tid & 1;
        float s = 0.f;
#pragma unroll
        for (int d0 = 0; d0 < 32; d0 += 8) {
            bf16x8 qv = *(const bf16x8*)&sQ[row * 72 + hf * 32 + d0];
#pragma unroll
            for (int j = 0; j < 8; j++) s += (float)qv[j] * ksst[hf * 32 + d0 + j];
        }
        s += __shfl_xor(s, 1);
        if (hf == 0) den2[row] = s;
    }

    // S = Q K^T  (each wave owns 64x64 quadrant)
    int wr = (w >> 1) * 64, wc = (w & 1) * 64;
    f32x4 acc[4][4] = {};
    const __bf16* kbase = kb + (size_t)(bh * 1024 + ch * 128) * 64;
#pragma unroll
    for (int ks = 0; ks < 2; ks++) {
        bf16x8 a[4], bfr[4];
#pragma unroll
        for (int mi = 0; mi < 4; mi++)
            a[mi] = *(const bf16x8*)&sQ[(wr + mi * 16 + (l & 15)) * 72 + ks * 32 + ((l >> 4) << 3)];
#pragma unroll
        for (int ni = 0; ni < 4; ni++)
            bfr[ni] = *(const bf16x8*)&kbase[(size_t)(wc + ni * 16 + (l & 15)) * 64 + ks * 32 + ((l >> 4) << 3)];
#pragma unroll
        for (int mi = 0; mi < 4; mi++)
#pragma unroll
            for (int ni = 0; ni < 4; ni++)
                acc[mi][ni] = MFMA16(a[mi], bfr[ni], acc[mi][ni]);
    }

    // mask (j<=i), row-sums, write P (bf16) to LDS
#pragma unroll
    for (int mi = 0; mi < 4; mi++) {
#pragma unroll
        for (int j = 0; j < 4; j++) {
            int row = wr + mi * 16 + ((l >> 4) << 2) + j;
            float rs = 0.f;
#pragma unroll
            for (int ni = 0; ni < 4; ni++) {
                int col = wc + ni * 16 + (l & 15);
                float v = acc[mi][ni][j];
                v = (col <= row) ? v : 0.f;
                rs += v;
                sP[row * 132 + col] = (__bf16)v;
            }
#pragma unroll
            for (int off = 1; off < 16; off <<= 1) rs += __shfl_xor(rs, off);
            if ((l & 15) == 0) dpart[w & 1][row] = rs;
        }
    }
    __syncthreads();

    // O = P @ V  +  Q @ KV_state   (each wave owns 32 rows x 64 cols)
    f32x4 o[2][4] = {};
    const __bf16* vbase = vtb + (size_t)bh * 65536 + ch * 128;
    const __bf16* mbase = Mstate + (size_t)blk * 4096;
#pragma unroll
    for (int ks = 0; ks < 4; ks++) {
        bf16x8 a[2], bfr[4];
#pragma unroll
        for (int mi = 0; mi < 2; mi++)
            a[mi] = *(const bf16x8*)&sP[(w * 32 + mi * 16 + (l & 15)) * 132 + ks * 32 + ((l >> 4) << 3)];
#pragma unroll
        for (int ni = 0; ni < 4; ni++)
            bfr[ni] = *(const bf16x8*)&vbase[(size_t)(ni * 16 + (l & 15)) * 1024 + ks * 32 + ((l >> 4) << 3)];
#pragma unroll
        for (int mi = 0; mi < 2; mi++)
#pragma unroll
            for (int ni = 0; ni < 4; ni++)
                o[mi][ni] = MFMA16(a[mi], bfr[ni], o[mi][ni]);
    }
#pragma unroll
    for (int ks = 0; ks < 2; ks++) {
        bf16x8 a[2], bfr[4];
#pragma unroll
        for (int mi = 0; mi < 2; mi++)
            a[mi] = *(const bf16x8*)&sQ[(w * 32 + mi * 16 + (l & 15)) * 72 + ks * 32 + ((l >> 4) << 3)];
#pragma unroll
        for (int ni = 0; ni < 4; ni++)
            bfr[ni] = *(const bf16x8*)&mbase[(size_t)(ni * 16 + (l & 15)) * 64 + ks * 32 + ((l >> 4) << 3)];
#pragma unroll
        for (int mi = 0; mi < 2; mi++)
#pragma unroll
            for (int ni = 0; ni < 4; ni++)
                o[mi][ni] = MFMA16(a[mi], bfr[ni], o[mi][ni]);
    }

    // normalize and write out [B*S][512] at head offset
    __bf16* obase = attn_out + ((size_t)(b * 1024 + ch * 128)) * 512 + h * 64;
#pragma unroll
    for (int mi = 0; mi < 2; mi++)
#pragma unroll
        for (int j = 0; j < 4; j++) {
            int row = w * 32 + mi * 16 + ((l >> 4) << 2) + j;
            float dn = den2[row] + dpart[0][row] + dpart[1][row] + 1e-6f;
#pragma unroll
            for (int ni = 0; ni < 4; ni++) {
                int col = ni * 16 + (l & 15);
                obase[(size_t)row * 512 + col] = (__bf16)(o[mi][ni][j] / dn);
            }
        }
}

// ----------------------------------------------------------------
extern "C" void kernel_launch(void* const* d_in, const int* in_sizes, int n_in,
                              void* d_out, int out_size, void* d_ws, size_t ws_size,
                              hipStream_t stream) {
    const float* x = (const float*)d_in[0];
    const float* Wq = (const float*)d_in[1];
    const float* Wk = (const float*)d_in[2];
    const float* Wv = (const float*)d_in[3];
    const float* Wo = (const float*)d_in[4];
    const float* bo = (const float*)d_in[5];
    const float* Wg = (const float*)d_in[6];
    const float* bg = (const float*)d_in[7];
    float* out = (float*)d_out;

    char* ws = (char*)d_ws;
    size_t off = 0;
    auto alloc = [&](size_t bytes) -> void* {
        void* p = ws + off;
        off += (bytes + 255) & ~(size_t)255;
        return p;
    };
    __bf16* xb    = (__bf16*)alloc((size_t)2048 * 512 * 2);
    __bf16* wqkvT = (__bf16*)alloc((size_t)1536 * 512 * 2);
    __bf16* woT   = (__bf16*)alloc((size_t)512 * 512 * 2);
    __bf16* wgT   = (__bf16*)alloc((size_t)512 * 1024 * 2);
    __bf16* qb    = (__bf16*)alloc((size_t)16 * 1024 * 64 * 2);
    __bf16* kb    = (__bf16*)alloc((size_t)16 * 1024 * 64 * 2);
    __bf16* ktb   = (__bf16*)alloc((size_t)16 * 64 * 1024 * 2);
    __bf16* vtb   = (__bf16*)alloc((size_t)16 * 64 * 1024 * 2);
    float*  Mc    = (float*)alloc((size_t)16 * 8 * 4096 * 4);
    __bf16* Mst   = (__bf16*)alloc((size_t)16 * 8 * 4096 * 2);
    float*  kss   = (float*)alloc((size_t)16 * 8 * 64 * 4);
    __bf16* attn  = (__bf16*)alloc((size_t)2048 * 512 * 2);
    float*  proj  = (float*)alloc((size_t)2048 * 512 * 4);
    __bf16* projb = (__bf16*)alloc((size_t)2048 * 512 * 2);

    prep_kernel<<<dim3(16, 32, 6), 256, 0, stream>>>(x, Wq, Wk, Wv, Wo, Wg, xb, wqkvT, woT, wgT);
    gemm_kernel<0, 128><<<dim3(16, 12), 256, 0, stream>>>(xb, nullptr, wqkvT, nullptr, nullptr,
                                                          nullptr, nullptr, nullptr, qb, kb, ktb,
                                                          vtb, 512);
    chunkstate_kernel<<<16, 256, 0, stream>>>(ktb, vtb, Mc, Mst, kss);
    attn_chunk_kernel<<<128, 256, 0, stream>>>(qb, kb, vtb, Mst, kss, attn);
    gemm_kernel<1, 64><<<dim3(16, 8), 256, 0, stream>>>(attn, nullptr, woT, bo, nullptr, nullptr,
                                                        proj, projb, nullptr, nullptr, nullptr,
                                                        nullptr, 512);
    gemm_kernel<2, 64><<<dim3(16, 8), 256, 0, stream>>>(xb, projb, wgT, bg, x, proj, out, nullptr,
                                                        nullptr, nullptr, nullptr, nullptr, 1024);
}